// Round 8
// baseline (128.801 us; speedup 1.0000x reference)
//
#include <hip/hip_runtime.h>

// Problem constants (fixed by setup_inputs: bs=8, N=M=4096, C=128)
#define BS 8
#define NN 4096
#define MM 4096
#define CC 128
#define XT 128            // x rows per block
#define YT 128            // y rows per t-tile
#define MH 2048           // y rows per block
#define NMT (MH / YT)     // 16 y-tiles per block
#define NPH (4 * NMT)     // 64 quarter-K phases per block
#define NXT (NN / XT)     // 32 x-tiles
#define QS (64 * 32)      // ushorts per wave-private quarter-K slice (4 KB)

#define FINF_BITS 0x7F800000u

typedef __attribute__((ext_vector_type(8))) short bf16x8;
typedef __attribute__((ext_vector_type(4))) float f32x4;

// counted vmcnt wait (n = allowed outstanding VMEM ops) -- PER-WAVE counter
#define WAITVn(n) asm volatile("s_waitcnt vmcnt(" #n ")" ::: "memory")
// rule #18: hipcc can hoist loads past inline-asm waitcnt; pin program order
#define SCHED_FENCE() __builtin_amdgcn_sched_barrier(0)

// RNE fp32 -> bf16 (inputs are finite normals)
__device__ inline ushort f2bf(float f) {
    unsigned u = __float_as_uint(f);
    unsigned r = (u + 0x7FFFu + ((u >> 16) & 1u)) >> 16;
    return (ushort)r;
}

// ---------------------------------------------------------------------------
// prep (y only): fp32->bf16 copy of set2 + exact fp32 y norms +
// rowmin/colmin=+inf + out=0. 8 elem/thread.
// ---------------------------------------------------------------------------
__global__ void ch_prep(const float* __restrict__ y,
                        ushort* __restrict__ y16, float* __restrict__ yn,
                        unsigned* __restrict__ rowmin, unsigned* __restrict__ colmin,
                        float* __restrict__ out) {
    int gid = blockIdx.x * blockDim.x + threadIdx.x;   // 524288 threads
    size_t i = (size_t)gid * 8;

    float4 w0 = *(const float4*)(y + i);
    float4 w1 = *(const float4*)(y + i + 4);
    ushort h[8] = {f2bf(w0.x), f2bf(w0.y), f2bf(w0.z), f2bf(w0.w),
                   f2bf(w1.x), f2bf(w1.y), f2bf(w1.z), f2bf(w1.w)};
    *(bf16x8*)(y16 + i) = *(bf16x8*)h;
    float sy = w0.x * w0.x + w0.y * w0.y + w0.z * w0.z + w0.w * w0.w +
               w1.x * w1.x + w1.y * w1.y + w1.z * w1.z + w1.w * w1.w;

#pragma unroll
    for (int mask = 1; mask <= 8; mask <<= 1)
        sy += __shfl_xor(sy, mask, 64);
    if ((threadIdx.x & 15) == 0)
        yn[gid >> 4] = sy;                 // 16 threads per 128-ch row

    if (gid < BS * NN) rowmin[gid] = FINF_BITS;
    if (gid < BS * MM) colmin[gid] = FINF_BITS;
    if (gid == 0) out[0] = 0.0f;
}

// ---------------------------------------------------------------------------
// wave-private stage: one quarter-K slice (this wave's 64 y-rows x 32 k =
// 4 KB) via global_load_lds width-16. 64 lanes x 4 loads; LDS linear
// [64 rows][4 chunk-slots of 16 B]; source chunk-swizzled c ^ (r&3) so the
// ds_read at slot quad^(rr&3) is bank-optimal (8-cyc streaming minimum).
// Counts 4 on the wave's vmcnt.
// ---------------------------------------------------------------------------
__device__ __forceinline__ void stage_yw(const ushort* __restrict__ Yb,
                                         ushort* __restrict__ buf,
                                         int tile, int kt, int lane, int wn) {
#pragma unroll
    for (int s = 0; s < 4; ++s) {
        int f = s * 64 + lane;           // 256 chunks = 64 rows x 4
        int r = f >> 2, cslot = f & 3;
        const ushort* g = Yb + (size_t)(tile * YT + wn * 64 + r) * CC +
                          kt * 32 + ((cslot ^ (r & 3)) * 8);
        ushort* l = buf + (size_t)(s * 64) * 8;   // uniform; HW adds lane*16
        __builtin_amdgcn_global_load_lds(
            (const __attribute__((address_space(1))) void*)g,
            (__attribute__((address_space(3))) void*)l, 16, 0, 0);
    }
}

// ---------------------------------------------------------------------------
// main kernel (R23): barrier-free wave-private pipeline. Floors per CU:
// MFMA 16.6 us (8192 mfma x 4.85 CU-cyc -- R19-R22's "310/SIMD" was a
// per-CU/per-SIMD units bug), LDS 11-15 us, VALU 10-19 us; R19's 50.6 us
// ~= their SUM: the pipes run serialized because all waves hit the same
// per-phase barrier in lockstep (and 3 waves/SIMD is register-blocked:
// 116 VGPR + 64 AGPR = 180 > 170). R22 (fewer barriers) regressed; acc-dbuf
// (R20/R21) spilled. Fix here: each wave stages ITS OWN 64-row quarter-K
// slices (4 KB, 3-deep rotation, vmcnt(4)-gated) and the main loop has NO
// s_barrier at all -- correctness needs only within-wave program order +
// the wave's own vmcnt (it reads only LDS it wrote). 8 waves/CU free-run
// and desync, overlapping MFMA/VALU/LDS/L2 across waves (m114 mechanism).
// Costs accepted: 2x staging writes, 2x L2 y-reads (both <= MFMA floor).
// Geometry/epilogue identical to R19; 512 blocks = 1 full generation.
// ---------------------------------------------------------------------------
__global__ __launch_bounds__(256, 2) void ch_tile(
    const float* __restrict__ Xf, const ushort* __restrict__ Y,
    const float* __restrict__ yn,
    unsigned* __restrict__ rowmin, unsigned* __restrict__ colmin) {

    __shared__ ushort pool[4 * 3 * QS];  // 48 KB: 4 waves x 3 slices; xs aliases
    __shared__ unsigned coltile[MH];     // 8 KB
    __shared__ unsigned rowtile[XT];     // 0.5 KB
    __shared__ float xnorm[XT];          // 0.5 KB
    __shared__ float ynld[MH];           // 8 KB (block's y norms)

    const int b  = blockIdx.x;           // 0..7 -> XCD pin (linear id % 8 == b)
    const int xt = blockIdx.y;           // 0..31
    const int mh = blockIdx.z;           // 0..1
    const int n0 = xt * XT;
    const int m0 = mh * MH;
    const int tid  = threadIdx.x;        // 0..255
    const int lane = tid & 63;
    const int wave = tid >> 6;           // 0..3
    const int lc   = lane & 15;          // A/B row, C col
    const int quad = lane >> 4;          // k-chunk, C row group
    const int wm = wave >> 1;            // x half (0/1)
    const int wn = wave & 1;             // y half (0/1)

    const ushort* Yb = Y + ((size_t)b * MM + m0) * CC;

    // ---- prologue A: stage x tile fp32 -> bf16 -> swizzled LDS (xs = pool);
    //      x norms; y norms -> LDS; coltile/rowtile init ----
    ushort* xs = pool;                   // 32 KB transient, dies after hoist
    const float* Xb = Xf + ((size_t)b * NN + n0) * CC;
    {
        float psum[8];
#pragma unroll
        for (int s = 0; s < 8; ++s) {
            int flat = s * 256 + tid;    // 2048 chunks = 128 rows x 16
            int r = flat >> 4, c = flat & 15;
            float4 v0 = *(const float4*)(Xb + (size_t)r * CC + c * 8);
            float4 v1 = *(const float4*)(Xb + (size_t)r * CC + c * 8 + 4);
            ushort h[8] = {f2bf(v0.x), f2bf(v0.y), f2bf(v0.z), f2bf(v0.w),
                           f2bf(v1.x), f2bf(v1.y), f2bf(v1.z), f2bf(v1.w)};
            *(bf16x8*)(xs + r * CC + (c ^ (r & 7)) * 8) = *(bf16x8*)h;
            psum[s] = v0.x * v0.x + v0.y * v0.y + v0.z * v0.z + v0.w * v0.w +
                      v1.x * v1.x + v1.y * v1.y + v1.z * v1.z + v1.w * v1.w;
        }
#pragma unroll
        for (int mask = 1; mask <= 8; mask <<= 1)
#pragma unroll
            for (int s = 0; s < 8; ++s)
                psum[s] += __shfl_xor(psum[s], mask, 64);
        if ((tid & 15) == 0) {
#pragma unroll
            for (int s = 0; s < 8; ++s)
                xnorm[s * 16 + (tid >> 4)] = psum[s];
        }
    }
    {
        const float* ynb = yn + (size_t)b * MM + m0;
#pragma unroll
        for (int s = 0; s < MH / 256; ++s)
            ynld[s * 256 + tid] = ynb[s * 256 + tid];
    }
    for (int c2 = tid; c2 < MH; c2 += 256) coltile[c2] = FINF_BITS;
    if (tid < XT) rowtile[tid] = FINF_BITS;

    __syncthreads();   // xs + xnorm + ynld + coltile ready

    // ---- prologue B: hoist this wave's A operand + norms into registers ----
    bf16x8 af[4][4];   // [k-chunk32 kt][row-group i] : 64 VGPR
    const int xrow = (wm * 64 + lc) * CC;
    const int xsw  = lc & 7;
#pragma unroll
    for (int kt = 0; kt < 4; ++kt)
#pragma unroll
        for (int i = 0; i < 4; ++i)
            af[kt][i] = *(const bf16x8*)(xs + xrow + i * 16 * CC +
                                         ((kt * 4 + quad) ^ xsw) * 8);

    float xnp[4][4];
#pragma unroll
    for (int i = 0; i < 4; ++i) {
        float4 t = *(const float4*)(&xnorm[wm * 64 + i * 16 + quad * 4]);
        xnp[i][0] = t.x; xnp[i][1] = t.y; xnp[i][2] = t.z; xnp[i][3] = t.w;
    }
    float rm[4][4];
#pragma unroll
    for (int i = 0; i < 4; ++i)
#pragma unroll
        for (int r = 0; r < 4; ++r) rm[i][r] = __builtin_inff();

    __syncthreads();   // xs dead; waves are INDEPENDENT from here to the flush

    // ---- wave-private 3-slice pipeline: stage phases 0,1 ----
    ushort* wslc = pool + wave * 3 * QS;
    stage_yw(Yb, wslc + 0 * QS, 0, 0, lane, wn);
    stage_yw(Yb, wslc + 1 * QS, 0, 1, lane, wn);
    WAITVn(4);                       // slice 0 landed; slice 1 in flight
    SCHED_FENCE();

    const f32x4 z = {0.f, 0.f, 0.f, 0.f};
    int rdw = 0;                     // this wave's current slice buffer

#pragma unroll 1
    for (int t = 0; t < NMT; ++t) {
        f32x4 acc[4][4];
        float ynr[4];
#pragma unroll
        for (int j = 0; j < 4; ++j)      // LDS read: no vmcnt impact
            ynr[j] = ynld[t * YT + wn * 64 + j * 16 + lc];

#pragma unroll
        for (int kt = 0; kt < 4; ++kt) {
            const int ph = 4 * t + kt;
            // stage slice ph+2 into the free buffer (4 loads)
            if (ph + 2 < NPH) {
                int wr = rdw + 2; if (wr >= 3) wr -= 3;
                stage_yw(Yb, wslc + wr * QS, (ph + 2) >> 2, (ph + 2) & 3,
                         lane, wn);
            }
            // compute from slice ph (landed): 4 yf reads + 16 MFMA
            const ushort* ybuf = wslc + rdw * QS;
            const int cs = (quad ^ (lc & 3)) * 8;   // bank-spread slot
            bf16x8 yf[4];
#pragma unroll
            for (int j = 0; j < 4; ++j)
                yf[j] = *(const bf16x8*)(ybuf + (j * 16 + lc) * 32 + cs);
            __builtin_amdgcn_s_setprio(1);
#pragma unroll
            for (int j = 0; j < 4; ++j)
#pragma unroll
                for (int i = 0; i < 4; ++i)
                    acc[i][j] = __builtin_amdgcn_mfma_f32_16x16x32_bf16(
                        af[kt][i], yf[j], (kt == 0) ? z : acc[i][j], 0, 0, 0);
            __builtin_amdgcn_s_setprio(0);

            if (kt == 3) {
                // ---- epilogue: d^2 mins (sqrt/clamp deferred) ----
                float cmv[4];
#pragma unroll
                for (int j = 0; j < 4; ++j) cmv[j] = __builtin_inff();
#pragma unroll
                for (int i = 0; i < 4; ++i) {
#pragma unroll
                    for (int j = 0; j < 4; ++j) {
                        f32x4 a = acc[i][j];
                        float e[4];
#pragma unroll
                        for (int r = 0; r < 4; ++r)
                            e[r] = xnp[i][r] + fmaf(-2.0f, a[r], ynr[j]);
#pragma unroll
                        for (int r = 0; r < 4; ++r)
                            rm[i][r] = fminf(rm[i][r], e[r]);
                        cmv[j] = fminf(cmv[j],
                                       fminf(fminf(e[0], e[1]),
                                             fminf(e[2], e[3])));
                    }
                }
#pragma unroll
                for (int mask = 16; mask <= 32; mask <<= 1)
#pragma unroll
                    for (int j = 0; j < 4; ++j)
                        cmv[j] = fminf(cmv[j], __shfl_xor(cmv[j], mask, 64));
                if (quad == 0) {
#pragma unroll
                    for (int j = 0; j < 4; ++j)
                        atomicMin(&coltile[t * YT + wn * 64 + j * 16 + lc],
                                  __float_as_uint(fmaxf(cmv[j], 0.0f)));
                }
            }

            // gate slice ph+1 (4 of this wave's loads may stay in flight)
            SCHED_FENCE();
            if (ph + 2 < NPH) { WAITVn(4); } else { WAITVn(0); }
            SCHED_FENCE();
            rdw = (rdw == 2) ? 0 : rdw + 1;
        }
    }

    // ---- row mins: reduce across the 16 lc lanes, LDS atomic once ----
#pragma unroll
    for (int mask = 1; mask <= 8; mask <<= 1)
#pragma unroll
        for (int i = 0; i < 4; ++i)
#pragma unroll
            for (int r = 0; r < 4; ++r)
                rm[i][r] = fminf(rm[i][r], __shfl_xor(rm[i][r], mask, 64));
    if (lc == 0) {
#pragma unroll
        for (int i = 0; i < 4; ++i)
#pragma unroll
            for (int r = 0; r < 4; ++r)
                atomicMin(&rowtile[wm * 64 + i * 16 + quad * 4 + r],
                          __float_as_uint(fmaxf(rm[i][r], 0.0f)));
    }

    // ---- flush tile minima with global atomics ----
    __syncthreads();
    if (tid < XT)
        atomicMin(&rowmin[(size_t)b * NN + n0 + tid], rowtile[tid]);
    for (int c2 = tid; c2 < MH; c2 += 256)
        atomicMin(&colmin[(size_t)b * MM + m0 + c2], coltile[c2]);
}

// ---------------------------------------------------------------------------
// finalize: total = (sum w1*sqrt(rowmin) + sum w2*sqrt(colmin)) / 2
// ---------------------------------------------------------------------------
__global__ void ch_finalize(const unsigned* __restrict__ rowmin,
                            const unsigned* __restrict__ colmin,
                            const float* __restrict__ w1,
                            const float* __restrict__ w2,
                            float* __restrict__ out) {
    int i = blockIdx.x * blockDim.x + threadIdx.x;
    int stride = gridDim.x * blockDim.x;
    float s = 0.f;
    for (int idx = i; idx < BS * NN; idx += stride)
        s += w1[idx] * sqrtf(__uint_as_float(rowmin[idx])) +
             w2[idx] * sqrtf(__uint_as_float(colmin[idx]));
#pragma unroll
    for (int off = 32; off > 0; off >>= 1) s += __shfl_down(s, off, 64);
    __shared__ float ls[4];
    int lane = threadIdx.x & 63, wv = threadIdx.x >> 6;
    if (lane == 0) ls[wv] = s;
    __syncthreads();
    if (threadIdx.x == 0) {
        float t = ls[0] + ls[1] + ls[2] + ls[3];
        atomicAdd(out, 0.5f * t);
    }
}

extern "C" void kernel_launch(void* const* d_in, const int* in_sizes, int n_in,
                              void* d_out, int out_size, void* d_ws, size_t ws_size,
                              hipStream_t stream) {
    const float* set1 = (const float*)d_in[0];
    const float* set2 = (const float*)d_in[1];
    const float* w1   = (const float*)d_in[2];
    const float* w2   = (const float*)d_in[3];
    float* out = (float*)d_out;

    // workspace layout (~8.5 MiB)
    ushort*   y16    = (ushort*)d_ws;                        // BS*MM*CC bf16 (8 MB)
    float*    yn     = (float*)(y16 + (size_t)BS * MM * CC); // 128 KB
    unsigned* rowmin = (unsigned*)(yn + BS * MM);            // 128 KB (d^2 bits)
    unsigned* colmin = rowmin + BS * NN;                     // 128 KB (d^2 bits)

    ch_prep<<<BS * MM * CC / 8 / 256, 256, 0, stream>>>(
        set2, y16, yn, rowmin, colmin, out);

    dim3 grid(BS, NXT, MM / MH);   // b fastest -> linear id % 8 == b == XCD
    ch_tile<<<grid, 256, 0, stream>>>(set1, y16, yn, rowmin, colmin);

    ch_finalize<<<64, 256, 0, stream>>>(rowmin, colmin, w1, w2, out);
}

// Round 9
// 126.945 us; speedup vs baseline: 1.0146x; 1.0146x over previous
//
#include <hip/hip_runtime.h>

// Problem constants (fixed by setup_inputs: bs=8, N=M=4096, C=128)
#define BS 8
#define NN 4096
#define MM 4096
#define CC 128
#define XT 128            // x rows per block
#define YT 128            // y rows per t-tile
#define MH 2048           // y rows per block
#define NMT (MH / YT)     // 16 y-tiles per block
#define NPH (2 * NMT)     // 32 half-K pipeline phases
#define NXT (NN / XT)     // 32 x-tiles
#define SLICE (YT * 64)   // ushorts per half-K slice (16 KB)

#define FINF_BITS 0x7F800000u

typedef __attribute__((ext_vector_type(8))) short bf16x8;
typedef __attribute__((ext_vector_type(16))) float f32x16;

// counted vmcnt wait (n = allowed outstanding VMEM ops)
#define WAITVn(n) asm volatile("s_waitcnt vmcnt(" #n ")" ::: "memory")
// rule #18: pin scheduling around barriers
#define SCHED_FENCE() __builtin_amdgcn_sched_barrier(0)

// RNE fp32 -> bf16 (inputs are finite normals)
__device__ inline ushort f2bf(float f) {
    unsigned u = __float_as_uint(f);
    unsigned r = (u + 0x7FFFu + ((u >> 16) & 1u)) >> 16;
    return (ushort)r;
}

// ---------------------------------------------------------------------------
// prep (y only): fp32->bf16 copy of set2 + exact fp32 y norms +
// rowmin/colmin=+inf + out=0. 8 elem/thread.
// ---------------------------------------------------------------------------
__global__ void ch_prep(const float* __restrict__ y,
                        ushort* __restrict__ y16, float* __restrict__ yn,
                        unsigned* __restrict__ rowmin, unsigned* __restrict__ colmin,
                        float* __restrict__ out) {
    int gid = blockIdx.x * blockDim.x + threadIdx.x;   // 524288 threads
    size_t i = (size_t)gid * 8;

    float4 w0 = *(const float4*)(y + i);
    float4 w1 = *(const float4*)(y + i + 4);
    ushort h[8] = {f2bf(w0.x), f2bf(w0.y), f2bf(w0.z), f2bf(w0.w),
                   f2bf(w1.x), f2bf(w1.y), f2bf(w1.z), f2bf(w1.w)};
    *(bf16x8*)(y16 + i) = *(bf16x8*)h;
    float sy = w0.x * w0.x + w0.y * w0.y + w0.z * w0.z + w0.w * w0.w +
               w1.x * w1.x + w1.y * w1.y + w1.z * w1.z + w1.w * w1.w;

#pragma unroll
    for (int mask = 1; mask <= 8; mask <<= 1)
        sy += __shfl_xor(sy, mask, 64);
    if ((threadIdx.x & 15) == 0)
        yn[gid >> 4] = sy;                 // 16 threads per 128-ch row

    if (gid < BS * NN) rowmin[gid] = FINF_BITS;
    if (gid < BS * MM) colmin[gid] = FINF_BITS;
    if (gid == 0) out[0] = 0.0f;
}

// stage one half-K slice (128 rows x 64 k = 16 KB) of y tile via
// global_load_lds width-16, dest lane-order, source chunk-swizzled c^(r&7).
// 256 threads: 1024 chunks -> 4 iterations. Counts 4 on vmcnt per wave.
__device__ __forceinline__ void stage_y(const ushort* __restrict__ Yb,
                                        ushort* __restrict__ buf,
                                        int tile, int half, int tid, int wave) {
#pragma unroll
    for (int s = 0; s < 4; ++s) {
        int f = s * 256 + tid;           // 1024 chunks = 128 rows x 8
        int r = f >> 3, cslot = f & 7;
        const ushort* g = Yb + (size_t)(tile * YT + r) * CC + half * 64 +
                          ((cslot ^ (r & 7)) * 8);
        ushort* l = buf + (size_t)(s * 256 + wave * 64) * 8;  // uniform; HW adds lane*16
        __builtin_amdgcn_global_load_lds(
            (const __attribute__((address_space(1))) void*)g,
            (__attribute__((address_space(3))) void*)l, 16, 0, 0);
    }
}

// ---------------------------------------------------------------------------
// main kernel (R24 = R19 schedule + 32x32x16 MFMA + no setprio). R19/R22/R23
// proved the limiter is invariant to sync structure (counted-vmcnt 50.6 /
// 1-barrier-per-tile 64 / barrier-free 55.9): the per-wave stream itself
// serializes matrix (~13us) + VALU (~20us) + DS (~15us) at 2 waves/SIMD.
// This round attacks the consumers: (a) 32x32x16 MFMA -- same FLOPs at
// 8.07 cyc vs 2x4.85 (m119, -17% matrix time) and HALF the MFMA issue
// slots (32 vs 64 per tile/wave); (b) s_setprio REMOVED (m190: hurts GEMM;
// at 2 waves/SIMD it starves the other wave's VALU/DS issue). Fragment
// layouts per m74/m101: A/B lane holds row/col=lane&31, k=(lane>>5)*8+e;
// C/D col=lane&31, row=(reg&3)+8*(reg>>2)+4*(lane>>5). xnp kept as 2x4
// float4 matching reg quads; rm[2][16]. LDS slice layout, c^(r&7) swizzle,
// stage_y, 3-buffer counted-vmcnt schedule: bit-identical to R19. The new
// B-read pattern (row=base+lane&31, chunk=2ks+hi) stays bank-uniform under
// the same swizzle. VGPR est ~216 unified (2 waves/SIMD).
// ---------------------------------------------------------------------------
__global__ __launch_bounds__(256, 2) void ch_tile(
    const float* __restrict__ Xf, const ushort* __restrict__ Y,
    const float* __restrict__ yn,
    unsigned* __restrict__ rowmin, unsigned* __restrict__ colmin) {

    __shared__ ushort pool[3 * SLICE];   // 48 KB: xs (32 KB) then 3 y slices
    __shared__ unsigned coltile[MH];     // 8 KB
    __shared__ unsigned rowtile[XT];     // 0.5 KB
    __shared__ float xnorm[XT];          // 0.5 KB
    __shared__ float ynld[MH];           // 8 KB (block's y norms)

    const int b  = blockIdx.x;           // 0..7 -> XCD pin (linear id % 8 == b)
    const int xt = blockIdx.y;           // 0..31
    const int mh = blockIdx.z;           // 0..1
    const int n0 = xt * XT;
    const int m0 = mh * MH;
    const int tid  = threadIdx.x;        // 0..255
    const int lane = tid & 63;
    const int wave = tid >> 6;           // 0..3
    const int l31  = lane & 31;          // A row / B col / C col
    const int hi   = lane >> 5;          // k-half selector, C row offset 4*hi
    const int lsw  = lane & 7;           // swizzle key (row&7 == lane&7)
    const int wm = wave >> 1;            // x half (0/1)
    const int wn = wave & 1;             // y half (0/1)

    const ushort* Yb = Y + ((size_t)b * MM + m0) * CC;

    // ---- prologue A: stage x tile fp32 -> bf16 -> swizzled LDS (xs = pool);
    //      x norms; y norms -> LDS; coltile/rowtile init ----
    ushort* xs = pool;
    const float* Xb = Xf + ((size_t)b * NN + n0) * CC;
    {
        float psum[8];
#pragma unroll
        for (int s = 0; s < 8; ++s) {
            int flat = s * 256 + tid;    // 2048 chunks = 128 rows x 16
            int r = flat >> 4, c = flat & 15;
            float4 v0 = *(const float4*)(Xb + (size_t)r * CC + c * 8);
            float4 v1 = *(const float4*)(Xb + (size_t)r * CC + c * 8 + 4);
            ushort h[8] = {f2bf(v0.x), f2bf(v0.y), f2bf(v0.z), f2bf(v0.w),
                           f2bf(v1.x), f2bf(v1.y), f2bf(v1.z), f2bf(v1.w)};
            *(bf16x8*)(xs + r * CC + (c ^ (r & 7)) * 8) = *(bf16x8*)h;
            psum[s] = v0.x * v0.x + v0.y * v0.y + v0.z * v0.z + v0.w * v0.w +
                      v1.x * v1.x + v1.y * v1.y + v1.z * v1.z + v1.w * v1.w;
        }
#pragma unroll
        for (int mask = 1; mask <= 8; mask <<= 1)
#pragma unroll
            for (int s = 0; s < 8; ++s)
                psum[s] += __shfl_xor(psum[s], mask, 64);
        if ((tid & 15) == 0) {
#pragma unroll
            for (int s = 0; s < 8; ++s)
                xnorm[s * 16 + (tid >> 4)] = psum[s];
        }
    }
    {
        const float* ynb = yn + (size_t)b * MM + m0;
#pragma unroll
        for (int s = 0; s < MH / 256; ++s)
            ynld[s * 256 + tid] = ynb[s * 256 + tid];
    }
    for (int c2 = tid; c2 < MH; c2 += 256) coltile[c2] = FINF_BITS;
    if (tid < XT) rowtile[tid] = FINF_BITS;

    __syncthreads();   // xs + xnorm + ynld + coltile ready

    // ---- prologue B: hoist this wave's A operand + norms into registers ----
    // af[ks][i]: x-row wm*64 + i*32 + l31, k = ks*16 + hi*8 + 0..7
    bf16x8 af[8][2];   // 16 frags x 4 VGPR = 64 VGPR
#pragma unroll
    for (int ks = 0; ks < 8; ++ks)
#pragma unroll
        for (int i = 0; i < 2; ++i) {
            const int row = wm * 64 + i * 32 + l31;
            af[ks][i] = *(const bf16x8*)(xs + row * CC +
                                         ((ks * 2 + hi) ^ lsw) * 8);
        }

    // xnp[i][q] = xnorm rows (wm*64 + i*32 + q*8 + 4*hi) + 0..3  (= reg quad q)
    float4 xnp[2][4];
#pragma unroll
    for (int i = 0; i < 2; ++i)
#pragma unroll
        for (int q = 0; q < 4; ++q)
            xnp[i][q] = *(const float4*)(&xnorm[wm * 64 + i * 32 + q * 8 + 4 * hi]);

    float rm[2][16];
#pragma unroll
    for (int i = 0; i < 2; ++i)
#pragma unroll
        for (int r = 0; r < 16; ++r) rm[i][r] = __builtin_inff();

    __syncthreads();   // all waves done reading xs: pool may be overwritten

    // ---- prologue C: stage slices 0,1 into buffers 0,1 ----
    stage_y(Yb, pool + 0 * SLICE, 0, 0, tid, wave);
    stage_y(Yb, pool + 1 * SLICE, 0, 1, tid, wave);
    WAITVn(4);                       // slice 0 landed; slice 1 in flight
    __builtin_amdgcn_s_barrier();
    SCHED_FENCE();

    int rd = 0;                      // buffer holding the current slice
    const f32x16 z = {0.f, 0.f, 0.f, 0.f, 0.f, 0.f, 0.f, 0.f,
                      0.f, 0.f, 0.f, 0.f, 0.f, 0.f, 0.f, 0.f};
    f32x16 acc[2][2];                // 64 AGPR

#pragma unroll 1
    for (int t = 0; t < NMT; ++t) {
        float ynr[2];

        // ================= phase h=0 (k 0..63) =================
        {
            const int ph = 2 * t;
            const ushort* ybuf = pool + rd * SLICE;
            if (ph + 2 < NPH) {
                int wr = rd + 2; if (wr >= 3) wr -= 3;
                stage_y(Yb, pool + wr * SLICE, (ph + 2) >> 1, (ph + 2) & 1,
                        tid, wave);
            }
#pragma unroll
            for (int j = 0; j < 2; ++j)       // LDS read: no vmcnt impact
                ynr[j] = ynld[t * YT + wn * 64 + j * 32 + l31];

#pragma unroll
            for (int ks = 0; ks < 4; ++ks) {
                bf16x8 yf[2];
#pragma unroll
                for (int j = 0; j < 2; ++j) {
                    const int row = wn * 64 + j * 32 + l31;
                    yf[j] = *(const bf16x8*)(ybuf + row * 64 +
                                             ((ks * 2 + hi) ^ lsw) * 8);
                }
#pragma unroll
                for (int j = 0; j < 2; ++j)
#pragma unroll
                    for (int i = 0; i < 2; ++i)
                        acc[i][j] = __builtin_amdgcn_mfma_f32_32x32x16_bf16(
                            af[ks][i], yf[j], (ks == 0) ? z : acc[i][j], 0, 0, 0);
            }
            SCHED_FENCE();
            if (ph + 2 < NPH) { WAITVn(4); } else { WAITVn(0); }
            __builtin_amdgcn_s_barrier();
            SCHED_FENCE();
            rd = (rd == 2) ? 0 : rd + 1;
        }

        // ================= phase h=1 (k 64..127) =================
        {
            const int ph = 2 * t + 1;
            const ushort* ybuf = pool + rd * SLICE;
            if (ph + 2 < NPH) {
                int wr = rd + 2; if (wr >= 3) wr -= 3;
                stage_y(Yb, pool + wr * SLICE, (ph + 2) >> 1, (ph + 2) & 1,
                        tid, wave);
            }
#pragma unroll
            for (int ks = 0; ks < 4; ++ks) {
                bf16x8 yf[2];
#pragma unroll
                for (int j = 0; j < 2; ++j) {
                    const int row = wn * 64 + j * 32 + l31;
                    yf[j] = *(const bf16x8*)(ybuf + row * 64 +
                                             ((ks * 2 + hi) ^ lsw) * 8);
                }
#pragma unroll
                for (int j = 0; j < 2; ++j)
#pragma unroll
                    for (int i = 0; i < 2; ++i)
                        acc[i][j] = __builtin_amdgcn_mfma_f32_32x32x16_bf16(
                            af[4 + ks][i], yf[j], acc[i][j], 0, 0, 0);
            }

            // ---- epilogue: d^2 mins (sqrt/clamp deferred) ----
            // C/D: col = wn*64 + j*32 + l31; row = i*32 + (reg&3)+8*(reg>>2)+4*hi
            float cmv[2] = {__builtin_inff(), __builtin_inff()};
#pragma unroll
            for (int i = 0; i < 2; ++i) {
#pragma unroll
                for (int j = 0; j < 2; ++j) {
                    f32x16 a = acc[i][j];
                    float m = __builtin_inff();
#pragma unroll
                    for (int q = 0; q < 4; ++q) {
                        float4 xq = xnp[i][q];
                        float e0 = xq.x + fmaf(-2.0f, a[q * 4 + 0], ynr[j]);
                        float e1 = xq.y + fmaf(-2.0f, a[q * 4 + 1], ynr[j]);
                        float e2 = xq.z + fmaf(-2.0f, a[q * 4 + 2], ynr[j]);
                        float e3 = xq.w + fmaf(-2.0f, a[q * 4 + 3], ynr[j]);
                        rm[i][q * 4 + 0] = fminf(rm[i][q * 4 + 0], e0);
                        rm[i][q * 4 + 1] = fminf(rm[i][q * 4 + 1], e1);
                        rm[i][q * 4 + 2] = fminf(rm[i][q * 4 + 2], e2);
                        rm[i][q * 4 + 3] = fminf(rm[i][q * 4 + 3], e3);
                        m = fminf(m, fminf(fminf(e0, e1), fminf(e2, e3)));
                    }
                    cmv[j] = fminf(cmv[j], m);
                }
            }
            // cross k-half (lane^32 holds the other 16 rows of the same col)
#pragma unroll
            for (int j = 0; j < 2; ++j)
                cmv[j] = fminf(cmv[j], __shfl_xor(cmv[j], 32, 64));
            if (hi == 0) {
#pragma unroll
                for (int j = 0; j < 2; ++j)
                    atomicMin(&coltile[t * YT + wn * 64 + j * 32 + l31],
                              __float_as_uint(fmaxf(cmv[j], 0.0f)));
            }

            SCHED_FENCE();
            if (ph + 2 < NPH) { WAITVn(4); } else { WAITVn(0); }
            __builtin_amdgcn_s_barrier();
            SCHED_FENCE();
            rd = (rd == 2) ? 0 : rd + 1;
        }
    }

    // ---- row mins: reduce across the 32 col-lanes (masks 1..16 only --
    //      lane^32 holds DIFFERENT rows), then LDS atomic from l31==0 ----
#pragma unroll
    for (int mask = 1; mask <= 16; mask <<= 1)
#pragma unroll
        for (int i = 0; i < 2; ++i)
#pragma unroll
            for (int r = 0; r < 16; ++r)
                rm[i][r] = fminf(rm[i][r], __shfl_xor(rm[i][r], mask, 64));
    if (l31 == 0) {
#pragma unroll
        for (int i = 0; i < 2; ++i)
#pragma unroll
            for (int q = 0; q < 4; ++q)
#pragma unroll
                for (int c = 0; c < 4; ++c)
                    atomicMin(&rowtile[wm * 64 + i * 32 + q * 8 + 4 * hi + c],
                              __float_as_uint(fmaxf(rm[i][q * 4 + c], 0.0f)));
    }

    // ---- flush tile minima with global atomics ----
    __syncthreads();
    if (tid < XT)
        atomicMin(&rowmin[(size_t)b * NN + n0 + tid], rowtile[tid]);
    for (int c2 = tid; c2 < MH; c2 += 256)
        atomicMin(&colmin[(size_t)b * MM + m0 + c2], coltile[c2]);
}

// ---------------------------------------------------------------------------
// finalize: total = (sum w1*sqrt(rowmin) + sum w2*sqrt(colmin)) / 2
// ---------------------------------------------------------------------------
__global__ void ch_finalize(const unsigned* __restrict__ rowmin,
                            const unsigned* __restrict__ colmin,
                            const float* __restrict__ w1,
                            const float* __restrict__ w2,
                            float* __restrict__ out) {
    int i = blockIdx.x * blockDim.x + threadIdx.x;
    int stride = gridDim.x * blockDim.x;
    float s = 0.f;
    for (int idx = i; idx < BS * NN; idx += stride)
        s += w1[idx] * sqrtf(__uint_as_float(rowmin[idx])) +
             w2[idx] * sqrtf(__uint_as_float(colmin[idx]));
#pragma unroll
    for (int off = 32; off > 0; off >>= 1) s += __shfl_down(s, off, 64);
    __shared__ float ls[4];
    int lane = threadIdx.x & 63, wv = threadIdx.x >> 6;
    if (lane == 0) ls[wv] = s;
    __syncthreads();
    if (threadIdx.x == 0) {
        float t = ls[0] + ls[1] + ls[2] + ls[3];
        atomicAdd(out, 0.5f * t);
    }
}

extern "C" void kernel_launch(void* const* d_in, const int* in_sizes, int n_in,
                              void* d_out, int out_size, void* d_ws, size_t ws_size,
                              hipStream_t stream) {
    const float* set1 = (const float*)d_in[0];
    const float* set2 = (const float*)d_in[1];
    const float* w1   = (const float*)d_in[2];
    const float* w2   = (const float*)d_in[3];
    float* out = (float*)d_out;

    // workspace layout (~8.5 MiB)
    ushort*   y16    = (ushort*)d_ws;                        // BS*MM*CC bf16 (8 MB)
    float*    yn     = (float*)(y16 + (size_t)BS * MM * CC); // 128 KB
    unsigned* rowmin = (unsigned*)(yn + BS * MM);            // 128 KB (d^2 bits)
    unsigned* colmin = rowmin + BS * NN;                     // 128 KB (d^2 bits)

    ch_prep<<<BS * MM * CC / 8 / 256, 256, 0, stream>>>(
        set2, y16, yn, rowmin, colmin, out);

    dim3 grid(BS, NXT, MM / MH);   // b fastest -> linear id % 8 == b == XCD
    ch_tile<<<grid, 256, 0, stream>>>(set1, y16, yn, rowmin, colmin);

    ch_finalize<<<64, 256, 0, stream>>>(rowmin, colmin, w1, w2, out);
}